// Round 9
// baseline (281.683 us; speedup 1.0000x reference)
//
#include <hip/hip_runtime.h>
#include <math.h>

typedef float  f4     __attribute__((ext_vector_type(4)));
typedef float  f32x4  __attribute__((ext_vector_type(4)));
typedef short  bf16x8 __attribute__((ext_vector_type(8)));
typedef unsigned short u16x8 __attribute__((ext_vector_type(8)));

#define S_ 2048
#define B_ 4
#define D_ 1024

__device__ __forceinline__ unsigned short f2bf(float f) {
    unsigned u = __builtin_bit_cast(unsigned, f);
    u = (u + 0x7FFFu + ((u >> 16) & 1u)) >> 16;
    return (unsigned short)u;
}

#define GLOAD16(gsrc, ldst) \
    __builtin_amdgcn_global_load_lds((const __attribute__((address_space(1))) void*)(gsrc), \
                                     (__attribute__((address_space(3))) void*)(ldst), 16, 0, 0)

#define VMCNT(n) asm volatile("s_waitcnt vmcnt(%0)" :: "n"(n) : "memory")

// ---------------------------------------------------------------------------
// Converters
// ---------------------------------------------------------------------------

__global__ __launch_bounds__(128)
void convert_x(const float* __restrict__ x, unsigned short* __restrict__ xb)
{
    const int bid = blockIdx.x;
    const int b = bid & (B_ - 1);
    const int s = bid >> 2;
    const int t = threadIdx.x;
    const float* in = x + (size_t)bid * D_ + t * 8;
    unsigned short* out = xb + ((size_t)b * S_ + s) * D_ + t * 8;
    f4 lo = *(const f4*)in;
    f4 hi = *(const f4*)(in + 4);
    u16x8 o;
#pragma unroll
    for (int j = 0; j < 4; j++) { o[j] = f2bf(lo[j]); o[4 + j] = f2bf(hi[j]); }
    *(u16x8*)out = o;
}

__global__ __launch_bounds__(256)
void convert_w(const float* __restrict__ W0, const float* __restrict__ W1,
               const float* __restrict__ W2, unsigned short* __restrict__ dst)
{
    const float* src = (blockIdx.z == 0) ? W0 : (blockIdx.z == 1) ? W1 : W2;
    unsigned short* d = dst + (size_t)blockIdx.z * D_ * D_;
    size_t i = ((size_t)blockIdx.x * 256 + threadIdx.x) * 8;
    f4 lo = *(const f4*)(src + i);
    f4 hi = *(const f4*)(src + i + 4);
    u16x8 o;
#pragma unroll
    for (int j = 0; j < 4; j++) { o[j] = f2bf(lo[j]); o[4 + j] = f2bf(hi[j]); }
    *(u16x8*)(d + i) = o;
}

__global__ __launch_bounds__(256)
void convert_bias(const float* __restrict__ b0, const float* __restrict__ b1,
                  const float* __restrict__ b2, float* __restrict__ bcat)
{
    int i = blockIdx.x * 256 + threadIdx.x;
    int z = i >> 10, j = i & 1023;
    bcat[i] = (z == 0) ? b0[j] : (z == 1) ? b1[j] : b2[j];
}

// V columns of qkv (pitch 3072, offset 2048) -> vt (B,D,S) bf16
__global__ __launch_bounds__(256)
void transpose_v(const unsigned short* __restrict__ qkv, unsigned short* __restrict__ vt)
{
    __shared__ unsigned short tile[64][72];
    const int t = threadIdx.x;
    const int s0 = blockIdx.x * 64, d0 = blockIdx.y * 64, b = blockIdx.z;
    const int rr = t >> 3, c8 = (t & 7) * 8;
#pragma unroll
    for (int p = 0; p < 2; p++) {
        int r = rr + p * 32;
        u16x8 v = *(const u16x8*)(qkv + ((size_t)b * S_ + s0 + r) * 3072 + 2048 + d0 + c8);
#pragma unroll
        for (int j = 0; j < 8; j++) tile[r][c8 + j] = v[j];
    }
    __syncthreads();
#pragma unroll
    for (int p = 0; p < 2; p++) {
        int r = rr + p * 32;
        u16x8 o;
#pragma unroll
        for (int j = 0; j < 8; j++) o[j] = tile[c8 + j][r];
        *(u16x8*)(vt + ((size_t)b * D_ + d0 + r) * S_ + s0 + c8) = o;
    }
}

// ---------------------------------------------------------------------------
// NT GEMM, 8 waves (2x4), BK=64, double-buffered LDS.
// Sync structure (PROVEN in r3): exactly one {vmcnt(0); s_barrier} per K-tile.
// Each wave drains ITS OWN staging loads; the barrier makes the tile landing
// collective.  No partial-landing assumptions (r4-r6's counted-vmcnt mapped
// quadrants to staged halves incorrectly: quadrants are per-WAVE-tile, so
// phase 1 touches both halves of both operands).
// T2 xor-swizzle (bases computed as (addr+64)^xor — r6 fix), T5 setprio,
// T1 bijective XCD swizzle.  PVMAP: batch = m0>>11 (merged-M attention PV).
// ---------------------------------------------------------------------------
template<int BM, int BN, bool BIAS, bool OBF16, bool PVMAP>
__global__ __launch_bounds__(512, 2)
void gemm8(const char* __restrict__ A_, int ldab,
           const char* __restrict__ B_in, int ldbb,
           const float* __restrict__ bias, void* __restrict__ C,
           int ldc, int K, float alpha,
           size_t zAb, size_t zBb, size_t zCe)
{
    constexpr int T   = 512;
    constexpr int WTM = BM / 2, WTN = BN / 4;
    constexpr int MR  = WTM / 16, NR = WTN / 16;   // 8, 4|2
    constexpr int MH  = MR / 2, NRH = NR / 2;      // 4, 2|1
    constexpr int ABYTES = BM * 128, BBYTES = BN * 128;
    constexpr int BUFB = ABYTES + BBYTES;
    constexpr int L   = BUFB / (T * 16);           // 8 | 6
    constexpr int LA2 = ABYTES / 2 / (T * 16);     // 2
    constexpr int LB2 = BBYTES / 2 / (T * 16);     // 2 | 1

    __shared__ char sm[2 * BUFB] __attribute__((aligned(128)));

    const int t  = threadIdx.x;
    const int w  = t >> 6, ln = t & 63;
    const int wr = w >> 2, wc = w & 3;
    const int c15 = ln & 15, k16 = ln >> 4;

    // T1 bijective XCD swizzle (nwg % 8 == 0 for all grids used)
    const int gx  = gridDim.x;
    const int nwg = gx * gridDim.y;
    const int l0  = blockIdx.y * gx + blockIdx.x;
    const int cpx = nwg >> 3;
    const int lsw = (l0 & 7) * cpx + (l0 >> 3);
    const int m0  = (lsw % gx) * BM;
    const int n0  = (lsw / gx) * BN;

    const int bz = PVMAP ? (m0 >> 11) : blockIdx.z;
    const char* Ab = A_  + (size_t)bz * zAb;
    const char* Bb = B_in + (size_t)bz * zBb;
    const int   am0 = PVMAP ? (m0 & (S_ - 1)) : m0;   // A row base within batch

    // ---- staging geometry: thread's region-local slot p = t*16, swizzled source
    const int p0 = t * 16;
    const int q0 = p0 ^ (((p0 >> 9) & 3) << 5);
    const int r0 = q0 >> 7, cb0 = q0 & 127;
    const char* srcA = Ab + (size_t)(am0 + r0) * ldab + cb0;
    const char* srcB = Bb + (size_t)(n0  + r0) * ldbb + cb0;
    const int wub = (t & ~63) * 16;

    // stage loads j = 0..L-1 into WB (order: Ah0, Bh0, Bh1, Ah1)
#define STAGE(KB, WB) \
    _Pragma("unroll") \
    for (int j = 0; j < L; ++j) { \
        if (j < LA2) { \
            GLOAD16(srcA + (size_t)(j * 64) * ldab + (KB), (WB) + j * 8192 + wub); \
        } else if (j < LA2 + LB2) { \
            int l = j - LA2; \
            GLOAD16(srcB + (size_t)(l * 64) * ldbb + (KB), (WB) + ABYTES + l * 8192 + wub); \
        } else if (j < LA2 + 2 * LB2) { \
            int l = j - LA2 - LB2; \
            GLOAD16(srcB + (size_t)(BN / 2 + l * 64) * ldbb + (KB), (WB) + ABYTES + BBYTES / 2 + l * 8192 + wub); \
        } else { \
            int l = j - LA2 - 2 * LB2; \
            GLOAD16(srcA + (size_t)(BM / 2 + l * 64) * ldab + (KB), (WB) + ABYTES / 2 + l * 8192 + wub); \
        } \
    }

    // ---- ds_read bases: swizzle applied AFTER the +64 k-half offset (r6 fix).
    const int qA  = (wr * WTM + c15) * 128 + k16 * 16;
    const int xA  = ((qA >> 9) & 3) << 5;
    const int bA0 = qA ^ xA;
    const int bA1 = (qA + 64) ^ xA;
    const int qB  = ABYTES + (wc * WTN + c15) * 128 + k16 * 16;
    const int xB  = ((qB >> 9) & 3) << 5;
    const int bB0 = qB ^ xB;
    const int bB1 = (qB + 64) ^ xB;

    bf16x8 Af[MH][2], Bf[2][NRH][2];
    f32x4 acc[MR][NR];
#pragma unroll
    for (int i = 0; i < MR; i++)
#pragma unroll
        for (int j = 0; j < NR; j++) acc[i][j] = (f32x4)0.f;

#define RDA(mh, RB) \
    _Pragma("unroll") for (int f = 0; f < MH; ++f) { \
        Af[f][0] = *(const bf16x8*)((RB) + bA0 + (mh) * (MH * 2048) + f * 2048); \
        Af[f][1] = *(const bf16x8*)((RB) + bA1 + (mh) * (MH * 2048) + f * 2048); }
#define RDB(nh, RB) \
    _Pragma("unroll") for (int g = 0; g < NRH; ++g) { \
        Bf[nh][g][0] = *(const bf16x8*)((RB) + bB0 + (nh) * (NRH * 2048) + g * 2048); \
        Bf[nh][g][1] = *(const bf16x8*)((RB) + bB1 + (nh) * (NRH * 2048) + g * 2048); }
#define QUAD(mh, nh) \
    __builtin_amdgcn_s_setprio(1); \
    _Pragma("unroll") for (int f = 0; f < MH; ++f) \
    _Pragma("unroll") for (int g = 0; g < NRH; ++g) { \
        acc[(mh)*MH+f][(nh)*NRH+g] = __builtin_amdgcn_mfma_f32_16x16x32_bf16( \
            Af[f][0], Bf[nh][g][0], acc[(mh)*MH+f][(nh)*NRH+g], 0, 0, 0); \
        acc[(mh)*MH+f][(nh)*NRH+g] = __builtin_amdgcn_mfma_f32_16x16x32_bf16( \
            Af[f][1], Bf[nh][g][1], acc[(mh)*MH+f][(nh)*NRH+g], 0, 0, 0); } \
    __builtin_amdgcn_s_setprio(0);

    // prologue: stage K-tile 0 into buf0 (drained at first loop-top wait)
    STAGE(0, sm);

    const int NT = K >> 6;
    int cur = 0;
    for (int kt = 0; kt < NT; ++kt) {
        VMCNT(0);                          // own staging loads landed
        __builtin_amdgcn_s_barrier();      // -> collectively landed; prev reads retired
        const char* rb  = sm + (cur ? BUFB : 0);
        char*       wb2 = sm + (cur ? 0 : BUFB);
        const size_t kbn = (size_t)(kt + 1) * 128;

        RDA(0, rb); RDB(0, rb);
        if (kt + 1 < NT) { STAGE(kbn, wb2); }   // next tile in flight across MFMA block
        QUAD(0, 0);
        RDB(1, rb);
        QUAD(0, 1);
        RDA(1, rb);
        QUAD(1, 0);
        QUAD(1, 1);
        cur ^= 1;
    }
    VMCNT(0);

    // ---- epilogue
    float bvv[NR];
#pragma unroll
    for (int j = 0; j < NR; j++)
        bvv[j] = BIAS ? bias[n0 + wc * WTN + j * 16 + c15] : 0.f;

    char* Cb = (char*)C;
#pragma unroll
    for (int mi = 0; mi < MR; mi++) {
        const int row = m0 + wr * WTM + mi * 16 + k16 * 4;
#pragma unroll
        for (int nj = 0; nj < NR; nj++) {
            const int col = n0 + wc * WTN + nj * 16 + c15;
#pragma unroll
            for (int r = 0; r < 4; r++) {
                float vv = acc[mi][nj][r] * alpha + bvv[nj];
                if (OBF16)
                    ((unsigned short*)Cb + (PVMAP ? 0 : blockIdx.z * zCe))[(size_t)(row + r) * ldc + col] = f2bf(vv);
                else
                    ((float*)Cb + (PVMAP ? 0 : blockIdx.z * zCe))[(size_t)(row + r) * ldc + col] = vv;
            }
        }
    }
#undef STAGE
#undef RDA
#undef RDB
#undef QUAD
}

// ---------------------------------------------------------------------------
// Row softmax: read f32 row of 2048, write bf16 row IN PLACE
// ---------------------------------------------------------------------------
__global__ __launch_bounds__(256)
void softmax_rows(float* __restrict__ P)
{
    float* p = P + (size_t)blockIdx.x * S_;
    const int t = threadIdx.x;

    f4 v0 = *(f4*)&p[t * 8];
    f4 v1 = *(f4*)&p[t * 8 + 4];

    float mx = v0[0];
#pragma unroll
    for (int j = 0; j < 4; j++) { mx = fmaxf(mx, v0[j]); mx = fmaxf(mx, v1[j]); }
#pragma unroll
    for (int off = 32; off > 0; off >>= 1) mx = fmaxf(mx, __shfl_xor(mx, off));

    __shared__ float rmax[4], rsum[4];
    if ((t & 63) == 0) rmax[t >> 6] = mx;
    __syncthreads();
    mx = fmaxf(fmaxf(rmax[0], rmax[1]), fmaxf(rmax[2], rmax[3]));

    float sum = 0.f;
#pragma unroll
    for (int j = 0; j < 4; j++) {
        v0[j] = __expf(v0[j] - mx); sum += v0[j];
        v1[j] = __expf(v1[j] - mx); sum += v1[j];
    }
#pragma unroll
    for (int off = 32; off > 0; off >>= 1) sum += __shfl_xor(sum, off);
    if ((t & 63) == 0) rsum[t >> 6] = sum;
    __syncthreads();
    sum = rsum[0] + rsum[1] + rsum[2] + rsum[3];

    float inv = 1.f / sum;
    unsigned short* ob = (unsigned short*)p;
    u16x8 o;
#pragma unroll
    for (int j = 0; j < 4; j++) { o[j] = f2bf(v0[j] * inv); o[4 + j] = f2bf(v1[j] * inv); }
    __syncthreads();
    *(u16x8*)&ob[t * 8] = o;
}

// ---------------------------------------------------------------------------

extern "C" void kernel_launch(void* const* d_in, const int* in_sizes, int n_in,
                              void* d_out, int out_size, void* d_ws, size_t ws_size,
                              hipStream_t stream)
{
    const float* x  = (const float*)d_in[0];
    const float* Wq = (const float*)d_in[1];
    const float* bq = (const float*)d_in[2];
    const float* Wk = (const float*)d_in[3];
    const float* bk = (const float*)d_in[4];
    const float* Wv = (const float*)d_in[5];
    const float* bv = (const float*)d_in[6];
    float* out = (float*)d_out;

    const size_t nTok = (size_t)B_ * S_;
    char* ws = (char*)d_ws;

    unsigned short* xb   = (unsigned short*)ws;   ws += nTok * D_ * 2;            // 16 MB
    unsigned short* wcat = (unsigned short*)ws;   ws += (size_t)3 * D_ * D_ * 2;  // 6 MB
    float*          bcat = (float*)ws;            ws += 3 * D_ * 4;
    unsigned short* qkv  = (unsigned short*)ws;   ws += nTok * 3 * D_ * 2;        // 48 MB
    unsigned short* vt   = (unsigned short*)ws;   ws += nTok * D_ * 2;            // 16 MB
    float*          sc   = (float*)ws;            ws += (size_t)B_ * S_ * S_ * 4; // 64 MB
    if ((size_t)(ws - (char*)d_ws) > ws_size) return;

    convert_x<<<dim3(S_ * B_), dim3(128), 0, stream>>>(x, xb);
    convert_w<<<dim3(512, 1, 3), dim3(256), 0, stream>>>(Wq, Wk, Wv, wcat);
    convert_bias<<<dim3(12), dim3(256), 0, stream>>>(bq, bk, bv, bcat);

    // Fused QKV: [8192 x 3072] = xb @ wcat^T + bias, bf16 out.  768 blocks = 3 full rounds.
    gemm8<256, 128, true, true, false><<<dim3(32, 24, 1), dim3(512), 0, stream>>>(
        (const char*)xb, D_ * 2, (const char*)wcat, D_ * 2, bcat, qkv,
        3 * D_, D_, 1.f, 0, 0, 0);

    transpose_v<<<dim3(S_ / 64, D_ / 64, B_), dim3(256), 0, stream>>>(qkv, vt);

    // scores = scale * q k^T per batch (z).  256 blocks = 1 full round.
    gemm8<256, 256, false, false, false><<<dim3(8, 8, B_), dim3(512), 0, stream>>>(
        (const char*)qkv, 3 * D_ * 2, (const char*)(qkv + D_), 3 * D_ * 2, nullptr, sc,
        S_, D_, 0.03125f, (size_t)S_ * 3 * D_ * 2, (size_t)S_ * 3 * D_ * 2, (size_t)S_ * S_);

    softmax_rows<<<dim3(B_ * S_), dim3(256), 0, stream>>>(sc);

    // out = P @ V (merged batches, M = 8192).  256 blocks = 1 full round.
    // A row pitch: sc rows are 2048 f32 = 8192 BYTES (bf16 P occupies first 4096 B).
    gemm8<256, 128, false, false, true><<<dim3(32, 8, 1), dim3(512), 0, stream>>>(
        (const char*)sc, S_ * 4, (const char*)vt, S_ * 2, nullptr, out,
        D_, S_, 1.f, (size_t)S_ * S_ * 4, (size_t)D_ * S_ * 2, 0);
}